// Round 1
// baseline (2377.670 us; speedup 1.0000x reference)
//
#include <hip/hip_runtime.h>

#define NTOK 32768
#define KEMB 4096
#define DDIM 256
#define DECAYF 0.99f
#define EPSF 1e-5f

// ---------------- workspace layout (float offsets) ----------------
#define WS_CE    0u        // 4096 floats: codebook sq-norms
#define WS_CNT   4096u     // 4096 floats: counts
#define WS_CSP   8192u     // 4096 floats: cs_pre
#define WS_N     12288u    // 1 float: n
#define WS_FLAGC 12289u    // 1 int: flag count
#define WS_TIDX  16384u    // 32768 ints: per-token argmin
#define WS_FLIST 49152u    // 32768 ints: flagged tokens
#define WS_DW    81920u    // 1048576 floats: dw segment sum
// total = 1130496 floats = 4.52 MB

// ---------------- output layout (float offsets) ----------------
#define OFF_Q  0ull                 // quantized  [32768,256]
#define OFF_E  8388608ull           // encodings  [32768,4096]
#define OFF_CB 142606336ull         // new_codebook [4096,256]
#define OFF_W  143654912ull         // new_ema_w    [4096,256]
#define OFF_CS 144703488ull         // cs [4096]

// K1: per-cluster squared norms, one wave per cluster row
__global__ __launch_bounds__(256) void ce_kernel(const float* __restrict__ cb,
                                                 float* __restrict__ ce) {
    int k = blockIdx.x * 4 + (threadIdx.x >> 6);
    int lane = threadIdx.x & 63;
    float4 v = *(const float4*)(cb + (size_t)k * DDIM + lane * 4);
    float s = v.x * v.x + v.y * v.y + v.z * v.z + v.w * v.w;
    #pragma unroll
    for (int o = 32; o > 0; o >>= 1) s += __shfl_down(s, o);
    if (lane == 0) ce[k] = s;
}

// K2: tiled distance + per-token argmin (+ second-best for near-tie flagging).
// Block: 256 threads = 16 tx (clusters) x 16 ty (tokens). 64 tokens/block.
// LDS holds transposed A/B chunks [64 d][64 t/c] stride 68 -> conflict-free b128 reads.
#define TSTRIDE 68
__global__ __launch_bounds__(256) void dist_kernel(const float* __restrict__ xg,
                                                   const float* __restrict__ cb,
                                                   const float* __restrict__ ceg,
                                                   int* __restrict__ tokIdx,
                                                   int* __restrict__ flagList,
                                                   int* __restrict__ flagCount) {
    __shared__ float As[64 * TSTRIDE];    // 17408 B
    __shared__ float Bs[64 * TSTRIDE];    // 17408 B
    __shared__ float redB1[64 * 16];
    __shared__ float redB2[64 * 16];
    __shared__ int   redI[64 * 16];       // 12288 B

    const int tid = threadIdx.x;
    const int tx = tid & 15, ty = tid >> 4;
    const int tok0 = blockIdx.x * 64;

    float best1[4], best2[4];
    int bidx[4];
    #pragma unroll
    for (int i = 0; i < 4; ++i) { best1[i] = 3.4e38f; best2[i] = 3.4e38f; bidx[i] = 0; }

    for (int nc = 0; nc < KEMB / 64; ++nc) {
        float acc[4][4];
        #pragma unroll
        for (int i = 0; i < 4; ++i)
            #pragma unroll
            for (int j = 0; j < 4; ++j) acc[i][j] = 0.0f;

        for (int dc = 0; dc < DDIM / 64; ++dc) {
            __syncthreads();
            // stage A^T and B^T chunks (transpose in LDS)
            #pragma unroll
            for (int r = 0; r < 4; ++r) {
                int lin = r * 256 + tid;          // 0..1023
                int t = lin >> 4, dv = lin & 15;  // t/c: 0..63, dv: 0..15
                float4 va = *(const float4*)(xg + ((size_t)(tok0 + t)) * DDIM + dc * 64 + dv * 4);
                As[(dv * 4 + 0) * TSTRIDE + t] = va.x;
                As[(dv * 4 + 1) * TSTRIDE + t] = va.y;
                As[(dv * 4 + 2) * TSTRIDE + t] = va.z;
                As[(dv * 4 + 3) * TSTRIDE + t] = va.w;
                float4 vb = *(const float4*)(cb + ((size_t)(nc * 64 + t)) * DDIM + dc * 64 + dv * 4);
                Bs[(dv * 4 + 0) * TSTRIDE + t] = vb.x;
                Bs[(dv * 4 + 1) * TSTRIDE + t] = vb.y;
                Bs[(dv * 4 + 2) * TSTRIDE + t] = vb.z;
                Bs[(dv * 4 + 3) * TSTRIDE + t] = vb.w;
            }
            __syncthreads();
            const float* ap = As + ty * 4;
            const float* bp = Bs + tx * 4;
            #pragma unroll 8
            for (int d = 0; d < 64; ++d) {
                float4 a4 = *(const float4*)(ap + d * TSTRIDE);
                float4 b4 = *(const float4*)(bp + d * TSTRIDE);
                acc[0][0] = fmaf(a4.x, b4.x, acc[0][0]);
                acc[0][1] = fmaf(a4.x, b4.y, acc[0][1]);
                acc[0][2] = fmaf(a4.x, b4.z, acc[0][2]);
                acc[0][3] = fmaf(a4.x, b4.w, acc[0][3]);
                acc[1][0] = fmaf(a4.y, b4.x, acc[1][0]);
                acc[1][1] = fmaf(a4.y, b4.y, acc[1][1]);
                acc[1][2] = fmaf(a4.y, b4.z, acc[1][2]);
                acc[1][3] = fmaf(a4.y, b4.w, acc[1][3]);
                acc[2][0] = fmaf(a4.z, b4.x, acc[2][0]);
                acc[2][1] = fmaf(a4.z, b4.y, acc[2][1]);
                acc[2][2] = fmaf(a4.z, b4.z, acc[2][2]);
                acc[2][3] = fmaf(a4.z, b4.w, acc[2][3]);
                acc[3][0] = fmaf(a4.w, b4.x, acc[3][0]);
                acc[3][1] = fmaf(a4.w, b4.y, acc[3][1]);
                acc[3][2] = fmaf(a4.w, b4.z, acc[3][2]);
                acc[3][3] = fmaf(a4.w, b4.w, acc[3][3]);
            }
        }
        // scores for this 64-cluster chunk; track best/second-best per token
        #pragma unroll
        for (int j = 0; j < 4; ++j) {
            int k = nc * 64 + tx * 4 + j;
            float cek = ceg[k];
            #pragma unroll
            for (int i = 0; i < 4; ++i) {
                float s = cek - 2.0f * acc[i][j];   // + ||x||^2 is constant per token
                if (s < best1[i]) { best2[i] = best1[i]; best1[i] = s; bidx[i] = k; }
                else if (s < best2[i]) { best2[i] = s; }
            }
        }
    }
    // block-level merge across the 16 tx candidates per token
    #pragma unroll
    for (int i = 0; i < 4; ++i) {
        int t = ty * 4 + i;
        redB1[t * 16 + tx] = best1[i];
        redB2[t * 16 + tx] = best2[i];
        redI[t * 16 + tx]  = bidx[i];
    }
    __syncthreads();
    if (tid < 64) {
        int t = tid;
        float b1 = 3.4e38f, b2 = 3.4e38f;
        int i1 = 0x7fffffff;
        for (int c = 0; c < 16; ++c) {
            float cb1 = redB1[t * 16 + c];
            float cb2 = redB2[t * 16 + c];
            int   ci  = redI[t * 16 + c];
            if (cb1 < b1 || (cb1 == b1 && ci < i1)) {
                b2 = fminf(b1, cb2);
                b1 = cb1; i1 = ci;
            } else {
                b2 = fminf(b2, cb1);
            }
        }
        int tok = tok0 + t;
        tokIdx[tok] = i1;
        if (b2 - b1 < 0.0625f) {   // near-tie: fp32 error (~1e-3) could flip argmin
            int slot = atomicAdd(flagCount, 1);
            flagList[slot] = tok;
        }
    }
}

// K3: fp64 exact re-resolution of flagged tokens (full 4096-cluster scan)
__global__ __launch_bounds__(256) void refine_kernel(const float* __restrict__ xg,
                                                     const float* __restrict__ cb,
                                                     int* __restrict__ tokIdx,
                                                     const int* __restrict__ flagList,
                                                     const int* __restrict__ flagCount) {
    __shared__ double xs[256];
    __shared__ double rb[256];
    __shared__ int    ri[256];
    int nf = *flagCount;
    for (int f = blockIdx.x; f < nf; f += gridDim.x) {
        int tok = flagList[f];
        __syncthreads();
        xs[threadIdx.x] = (double)xg[(size_t)tok * DDIM + threadIdx.x];
        __syncthreads();
        double best = 1e300;
        int bi = 0x7fffffff;
        for (int kk = 0; kk < KEMB / 256; ++kk) {
            int k = kk * 256 + threadIdx.x;
            const float* e = cb + (size_t)k * DDIM;
            double s = 0.0;
            for (int d = 0; d < DDIM; ++d) {
                double ed = (double)e[d];
                s += ed * ed - 2.0 * ed * xs[d];
            }
            if (s < best) { best = s; bi = k; }   // k ascending per thread -> first-min kept
        }
        rb[threadIdx.x] = best;
        ri[threadIdx.x] = bi;
        __syncthreads();
        if (threadIdx.x == 0) {
            double b = rb[0]; int i1 = ri[0];
            for (int c = 1; c < 256; ++c) {
                if (rb[c] < b || (rb[c] == b && ri[c] < i1)) { b = rb[c]; i1 = ri[c]; }
            }
            tokIdx[tok] = i1;
        }
        __syncthreads();
    }
}

// K4: per-token scatter: quantized row, one-hot 1.0, dw/counts atomics
__global__ __launch_bounds__(64) void scatter_kernel(const float* __restrict__ xg,
                                                     const float* __restrict__ cb,
                                                     const int* __restrict__ tokIdx,
                                                     float* __restrict__ quant,
                                                     float* __restrict__ enc,
                                                     float* __restrict__ dw,
                                                     float* __restrict__ counts) {
    int tok = blockIdx.x;
    int lane = threadIdx.x;
    int k = tokIdx[tok];
    float4 e = *(const float4*)(cb + (size_t)k * DDIM + lane * 4);
    *(float4*)(quant + (size_t)tok * DDIM + lane * 4) = e;
    float4 xv = *(const float4*)(xg + (size_t)tok * DDIM + lane * 4);
    float* dwr = dw + (size_t)k * DDIM + lane * 4;
    atomicAdd(dwr + 0, xv.x);
    atomicAdd(dwr + 1, xv.y);
    atomicAdd(dwr + 2, xv.z);
    atomicAdd(dwr + 3, xv.w);
    if (lane == 0) {
        enc[(size_t)tok * KEMB + k] = 1.0f;
        atomicAdd(counts + k, 1.0f);
    }
}

// K5: cs_pre = ema_cs*decay + (1-decay)*counts ; n = sum(cs_pre)
__global__ __launch_bounds__(256) void cs_kernel(const float* __restrict__ ema_cs,
                                                 const float* __restrict__ counts,
                                                 float* __restrict__ cs_pre,
                                                 float* __restrict__ nptr) {
    int k = blockIdx.x * 256 + threadIdx.x;
    float c = ema_cs[k] * DECAYF + (1.0f - DECAYF) * counts[k];
    cs_pre[k] = c;
    float s = c;
    #pragma unroll
    for (int o = 32; o > 0; o >>= 1) s += __shfl_down(s, o);
    __shared__ float red[4];
    int lane = threadIdx.x & 63, w = threadIdx.x >> 6;
    if (lane == 0) red[w] = s;
    __syncthreads();
    if (threadIdx.x == 0) atomicAdd(nptr, red[0] + red[1] + red[2] + red[3]);
}

// K6: epilogue — new_ema_w, laplace-smoothed cs, new_codebook
__global__ __launch_bounds__(256) void epi_kernel(const float* __restrict__ ema_w,
                                                  const float* __restrict__ dw,
                                                  const float* __restrict__ cs_pre,
                                                  const float* __restrict__ nptr,
                                                  float* __restrict__ new_cb,
                                                  float* __restrict__ new_w,
                                                  float* __restrict__ cs_out) {
    int gid = blockIdx.x * 256 + threadIdx.x;   // 0 .. 1048575
    int k = gid >> 8, d = gid & 255;
    float n = *nptr;
    float csp = cs_pre[k];
    float cs = (csp + EPSF) / (n + (float)KEMB * EPSF) * n;
    float w = ema_w[gid] * DECAYF + (1.0f - DECAYF) * dw[gid];
    new_w[gid] = w;
    new_cb[gid] = w / cs;
    if (d == 0) cs_out[k] = cs;
}

extern "C" void kernel_launch(void* const* d_in, const int* in_sizes, int n_in,
                              void* d_out, int out_size, void* d_ws, size_t ws_size,
                              hipStream_t stream) {
    const float* xg     = (const float*)d_in[0];   // [32768,256]
    const float* cbg    = (const float*)d_in[1];   // [4096,256]
    const float* ema_w  = (const float*)d_in[2];   // [4096,256]
    const float* ema_cs = (const float*)d_in[3];   // [4096]

    float* out = (float*)d_out;
    float* ws  = (float*)d_ws;

    float* quant  = out + OFF_Q;
    float* enc    = out + OFF_E;
    float* new_cb = out + OFF_CB;
    float* new_w  = out + OFF_W;
    float* cs_out = out + OFF_CS;

    float* ce      = ws + WS_CE;
    float* counts  = ws + WS_CNT;
    float* cs_pre  = ws + WS_CSP;
    float* nptr    = ws + WS_N;
    int*   flagCnt = (int*)(ws + WS_FLAGC);
    int*   tokIdx  = (int*)(ws + WS_TIDX);
    int*   flist   = (int*)(ws + WS_FLIST);
    float* dw      = ws + WS_DW;

    // zero-init (d_out / d_ws are poisoned with 0xAA before every call)
    hipMemsetAsync(enc, 0, (size_t)NTOK * KEMB * sizeof(float), stream);   // 512 MB one-hot zeros
    hipMemsetAsync(counts, 0, KEMB * sizeof(float), stream);
    hipMemsetAsync(nptr, 0, 2 * sizeof(float), stream);                    // n + flagCount
    hipMemsetAsync(dw, 0, (size_t)KEMB * DDIM * sizeof(float), stream);

    ce_kernel<<<KEMB / 4, 256, 0, stream>>>(cbg, ce);
    dist_kernel<<<NTOK / 64, 256, 0, stream>>>(xg, cbg, ce, tokIdx, flist, flagCnt);
    refine_kernel<<<256, 256, 0, stream>>>(xg, cbg, tokIdx, flist, flagCnt);
    scatter_kernel<<<NTOK, 64, 0, stream>>>(xg, cbg, tokIdx, quant, enc, dw, counts);
    cs_kernel<<<KEMB / 256, 256, 0, stream>>>(ema_cs, counts, cs_pre, nptr);
    epi_kernel<<<(KEMB * DDIM) / 256, 256, 0, stream>>>(ema_w, dw, cs_pre, nptr,
                                                        new_cb, new_w, cs_out);
}

// Round 2
// 1283.024 us; speedup vs baseline: 1.8532x; 1.8532x over previous
//
#include <hip/hip_runtime.h>
#include <hip/hip_bf16.h>

#define NTOK 32768
#define KEMB 4096
#define DDIM 256
#define DECAYF 0.99f
#define EPSF 1e-5f

// ---------------- workspace layout (BYTE offsets) ----------------
#define B_AHAT  0ull          // 32768*768 bf16 = 50331648 B  [Xh|Xl|Xh]
#define B_BHAT  50331648ull   // 4096*768 bf16  = 6291456 B   [Ch|Ch|Cl]
#define B_PART  56623104ull   // 32768*64 float4 = 33554432 B  per-64col-chunk (b1,b2,idx)
#define B_CE    90177536ull   // 4096 f32
#define B_CNT   90193920ull   // 4096 f32
#define B_CSP   90210304ull   // 4096 f32
#define B_NPTR  90226688ull   // f32 n
#define B_FLAGC 90226692ull   // int flag count
#define B_TIDX  90226752ull   // 32768 int
#define B_FLIST 90357824ull   // 32768 int
#define B_DW    90488896ull   // 4096*256 f32 = 4194304 B
// total ~94.7 MB

// ---------------- output layout (float offsets) ----------------
#define OFF_Q  0ull                 // quantized  [32768,256]
#define OFF_E  8388608ull           // encodings  [32768,4096]
#define OFF_CB 142606336ull         // new_codebook [4096,256]
#define OFF_W  143654912ull         // new_ema_w    [4096,256]
#define OFF_CS 144703488ull         // cs [4096]

typedef __attribute__((ext_vector_type(8))) unsigned short us8;
typedef __attribute__((ext_vector_type(8))) short bf16x8;
typedef __attribute__((ext_vector_type(4))) float f32x4;

// ---- split fp32 -> (hi, lo) bf16, Ahat = [Xh | Xl | Xh] along K ----
__global__ __launch_bounds__(256) void splitA_kernel(const float* __restrict__ x,
                                                     unsigned short* __restrict__ Ahat) {
    int gid = blockIdx.x * 256 + threadIdx.x;   // 0 .. 32768*32-1
    int i = gid >> 5;
    int c = gid & 31;                           // 8-elem chunk
    const float* xp = x + (size_t)i * DDIM + c * 8;
    us8 hi, lo;
    #pragma unroll
    for (int t = 0; t < 8; ++t) {
        float v = xp[t];
        __hip_bfloat16 h = __float2bfloat16(v);
        float hf = __bfloat162float(h);
        __hip_bfloat16 l = __float2bfloat16(v - hf);
        hi[t] = *(unsigned short*)&h;
        lo[t] = *(unsigned short*)&l;
    }
    unsigned short* row = Ahat + (size_t)i * 768 + c * 8;
    *(us8*)(row)       = hi;
    *(us8*)(row + 256) = lo;
    *(us8*)(row + 512) = hi;
}

// ---- Bhat = [Ch | Ch | Cl] along K ----
__global__ __launch_bounds__(256) void splitB_kernel(const float* __restrict__ cb,
                                                     unsigned short* __restrict__ Bhat) {
    int gid = blockIdx.x * 256 + threadIdx.x;   // 0 .. 4096*32-1
    int j = gid >> 5;
    int c = gid & 31;
    const float* cp = cb + (size_t)j * DDIM + c * 8;
    us8 hi, lo;
    #pragma unroll
    for (int t = 0; t < 8; ++t) {
        float v = cp[t];
        __hip_bfloat16 h = __float2bfloat16(v);
        float hf = __bfloat162float(h);
        __hip_bfloat16 l = __float2bfloat16(v - hf);
        hi[t] = *(unsigned short*)&h;
        lo[t] = *(unsigned short*)&l;
    }
    unsigned short* row = Bhat + (size_t)j * 768 + c * 8;
    *(us8*)(row)       = hi;
    *(us8*)(row + 256) = hi;
    *(us8*)(row + 512) = lo;
}

// ---- per-cluster squared norms (fp32), one wave per cluster row ----
__global__ __launch_bounds__(256) void ce_kernel(const float* __restrict__ cb,
                                                 float* __restrict__ ce) {
    int k = blockIdx.x * 4 + (threadIdx.x >> 6);
    int lane = threadIdx.x & 63;
    float4 v = *(const float4*)(cb + (size_t)k * DDIM + lane * 4);
    float s = v.x * v.x + v.y * v.y + v.z * v.z + v.w * v.w;
    #pragma unroll
    for (int o = 32; o > 0; o >>= 1) s += __shfl_down(s, o);
    if (lane == 0) ce[k] = s;
}

// ---- bf16 MFMA GEMM (M=32768, N=4096, K=768, both row-major [*,K]) with
// fused per-row argmin over the block's 128 columns. m97 structure:
// 128x128 tile, BK=32, global_load_lds width-16, ds_read_b128 frags.
__global__ __launch_bounds__(256) void gemm_argmin_kernel(
        const unsigned short* __restrict__ Ahat,
        const unsigned short* __restrict__ Bhat,
        const float* __restrict__ ceg,
        float4* __restrict__ part) {
    __shared__ unsigned short As[128 * 32];   // 8 KB
    __shared__ unsigned short Bs[128 * 32];   // 8 KB
    const int tid  = threadIdx.x;
    const int lane = tid & 63;
    const int wave = tid >> 6;
    const int wm = wave >> 1, wn = wave & 1;  // 2x2 wave grid, 64x64 per wave
    const int mb = blockIdx.x, nb = blockIdx.y;
    const int col = lane & 15, q = lane >> 4;

    // staging: thread t loads 16B; rows 0..63 then 64..127 of the 128x32 chunk
    const int srow  = tid >> 2;
    const int skoff = (tid & 3) * 8;
    const unsigned short* ag = Ahat + (size_t)(mb * 128 + srow) * 768 + skoff;
    const unsigned short* bg = Bhat + (size_t)(nb * 128 + srow) * 768 + skoff;

    f32x4 zero = {0.f, 0.f, 0.f, 0.f};
    f32x4 acc[4][4];
    #pragma unroll
    for (int i = 0; i < 4; ++i)
        #pragma unroll
        for (int j = 0; j < 4; ++j) acc[i][j] = zero;

    for (int kt = 0; kt < 24; ++kt) {
        __syncthreads();
        __builtin_amdgcn_global_load_lds(
            (const __attribute__((address_space(1))) void*)(ag + kt * 32),
            (__attribute__((address_space(3))) void*)(As + tid * 8), 16, 0, 0);
        __builtin_amdgcn_global_load_lds(
            (const __attribute__((address_space(1))) void*)(ag + 64 * 768 + kt * 32),
            (__attribute__((address_space(3))) void*)(As + 2048 + tid * 8), 16, 0, 0);
        __builtin_amdgcn_global_load_lds(
            (const __attribute__((address_space(1))) void*)(bg + kt * 32),
            (__attribute__((address_space(3))) void*)(Bs + tid * 8), 16, 0, 0);
        __builtin_amdgcn_global_load_lds(
            (const __attribute__((address_space(1))) void*)(bg + 64 * 768 + kt * 32),
            (__attribute__((address_space(3))) void*)(Bs + 2048 + tid * 8), 16, 0, 0);
        __syncthreads();

        bf16x8 a[4], b[4];
        const bf16x8* Av = (const bf16x8*)As;
        const bf16x8* Bv = (const bf16x8*)Bs;
        #pragma unroll
        for (int i = 0; i < 4; ++i) a[i] = Av[(wm * 64 + i * 16 + col) * 4 + q];
        #pragma unroll
        for (int j = 0; j < 4; ++j) b[j] = Bv[(wn * 64 + j * 16 + col) * 4 + q];
        #pragma unroll
        for (int i = 0; i < 4; ++i)
            #pragma unroll
            for (int j = 0; j < 4; ++j)
                acc[i][j] = __builtin_amdgcn_mfma_f32_16x16x32_bf16(a[i], b[j], acc[i][j], 0, 0, 0);
    }

    // epilogue: s = ||c||^2 - 2*dot (argmin-equivalent; ||x||^2 constant per row).
    // C/D layout: col = lane&15, row = q*4 + reg. Reduce over columns:
    // per (i,reg) merge j in-register, then width-16 xor-shuffle across the 16 cols.
    float ce_j[4];
    #pragma unroll
    for (int j = 0; j < 4; ++j) ce_j[j] = ceg[nb * 128 + wn * 64 + j * 16 + col];

    #pragma unroll
    for (int i = 0; i < 4; ++i) {
        #pragma unroll
        for (int r = 0; r < 4; ++r) {
            float b1 = 3.4e38f, b2 = 3.4e38f;
            int i1 = 0x7fffffff;
            #pragma unroll
            for (int j = 0; j < 4; ++j) {
                float s = ce_j[j] - 2.0f * acc[i][j][r];
                int n = nb * 128 + wn * 64 + j * 16 + col;
                if (s < b1) { b2 = b1; b1 = s; i1 = n; }
                else if (s < b2) { b2 = s; }
            }
            #pragma unroll
            for (int m = 1; m < 16; m <<= 1) {
                float ob1 = __shfl_xor(b1, m, 16);
                float ob2 = __shfl_xor(b2, m, 16);
                int   oi  = __shfl_xor(i1, m, 16);
                bool take = (ob1 < b1) || (ob1 == b1 && oi < i1);
                float nb2 = take ? fminf(b1, ob2) : fminf(b2, ob1);
                if (take) { b1 = ob1; i1 = oi; }
                b2 = nb2;
            }
            if (col == i * 4 + r) {   // unique writer lane per (q,i,r)
                int mrow = mb * 128 + wm * 64 + i * 16 + q * 4 + r;
                float4 p;
                p.x = b1; p.y = b2; p.z = __int_as_float(i1); p.w = 0.0f;
                part[(size_t)mrow * 64 + nb * 2 + wn] = p;
            }
        }
    }
}

// ---- merge 64 column-chunk partials per row; flag near-ties ----
__global__ __launch_bounds__(256) void argmin_reduce_kernel(
        const float4* __restrict__ part,
        int* __restrict__ tokIdx,
        int* __restrict__ flist,
        int* __restrict__ flagCount) {
    int row = blockIdx.x * 4 + (threadIdx.x >> 6);
    int lane = threadIdx.x & 63;
    float4 p = part[(size_t)row * 64 + lane];
    float b1 = p.x, b2 = p.y;
    int i1 = __float_as_int(p.z);
    #pragma unroll
    for (int m = 1; m < 64; m <<= 1) {
        float ob1 = __shfl_xor(b1, m);
        float ob2 = __shfl_xor(b2, m);
        int   oi  = __shfl_xor(i1, m);
        bool take = (ob1 < b1) || (ob1 == b1 && oi < i1);
        float nb2 = take ? fminf(b1, ob2) : fminf(b2, ob1);
        if (take) { b1 = ob1; i1 = oi; }
        b2 = nb2;
    }
    if (lane == 0) {
        tokIdx[row] = i1;
        if (b2 - b1 < 0.0625f) {   // near-tie vs split-bf16 error (~1e-3): refine
            int slot = atomicAdd(flagCount, 1);
            flist[slot] = row;
        }
    }
}

// ---- fp64 exact re-resolution of flagged tokens ----
__global__ __launch_bounds__(256) void refine_kernel(const float* __restrict__ xg,
                                                     const float* __restrict__ cb,
                                                     int* __restrict__ tokIdx,
                                                     const int* __restrict__ flagList,
                                                     const int* __restrict__ flagCount) {
    __shared__ double xs[256];
    __shared__ double rb[256];
    __shared__ int    ri[256];
    int nf = *flagCount;
    for (int f = blockIdx.x; f < nf; f += gridDim.x) {
        int tok = flagList[f];
        __syncthreads();
        xs[threadIdx.x] = (double)xg[(size_t)tok * DDIM + threadIdx.x];
        __syncthreads();
        double best = 1e300;
        int bi = 0x7fffffff;
        for (int kk = 0; kk < KEMB / 256; ++kk) {
            int k = kk * 256 + threadIdx.x;
            const float* e = cb + (size_t)k * DDIM;
            double s = 0.0;
            for (int d = 0; d < DDIM; ++d) {
                double ed = (double)e[d];
                s += ed * ed - 2.0 * ed * xs[d];
            }
            if (s < best) { best = s; bi = k; }
        }
        rb[threadIdx.x] = best;
        ri[threadIdx.x] = bi;
        __syncthreads();
        if (threadIdx.x == 0) {
            double b = rb[0]; int i1 = ri[0];
            for (int c = 1; c < 256; ++c) {
                if (rb[c] < b || (rb[c] == b && ri[c] < i1)) { b = rb[c]; i1 = ri[c]; }
            }
            tokIdx[tok] = i1;
        }
        __syncthreads();
    }
}

// ---- per-token scatter: quantized row, one-hot 1.0, dw/counts atomics ----
__global__ __launch_bounds__(64) void scatter_kernel(const float* __restrict__ xg,
                                                     const float* __restrict__ cb,
                                                     const int* __restrict__ tokIdx,
                                                     float* __restrict__ quant,
                                                     float* __restrict__ enc,
                                                     float* __restrict__ dw,
                                                     float* __restrict__ counts) {
    int tok = blockIdx.x;
    int lane = threadIdx.x;
    int k = tokIdx[tok];
    float4 e = *(const float4*)(cb + (size_t)k * DDIM + lane * 4);
    *(float4*)(quant + (size_t)tok * DDIM + lane * 4) = e;
    float4 xv = *(const float4*)(xg + (size_t)tok * DDIM + lane * 4);
    float* dwr = dw + (size_t)k * DDIM + lane * 4;
    atomicAdd(dwr + 0, xv.x);
    atomicAdd(dwr + 1, xv.y);
    atomicAdd(dwr + 2, xv.z);
    atomicAdd(dwr + 3, xv.w);
    if (lane == 0) {
        enc[(size_t)tok * KEMB + k] = 1.0f;
        atomicAdd(counts + k, 1.0f);
    }
}

// ---- cs_pre = ema_cs*decay + (1-decay)*counts ; n = sum(cs_pre) ----
__global__ __launch_bounds__(256) void cs_kernel(const float* __restrict__ ema_cs,
                                                 const float* __restrict__ counts,
                                                 float* __restrict__ cs_pre,
                                                 float* __restrict__ nptr) {
    int k = blockIdx.x * 256 + threadIdx.x;
    float c = ema_cs[k] * DECAYF + (1.0f - DECAYF) * counts[k];
    cs_pre[k] = c;
    float s = c;
    #pragma unroll
    for (int o = 32; o > 0; o >>= 1) s += __shfl_down(s, o);
    __shared__ float red[4];
    int lane = threadIdx.x & 63, w = threadIdx.x >> 6;
    if (lane == 0) red[w] = s;
    __syncthreads();
    if (threadIdx.x == 0) atomicAdd(nptr, red[0] + red[1] + red[2] + red[3]);
}

// ---- epilogue: new_ema_w, laplace-smoothed cs, new_codebook ----
__global__ __launch_bounds__(256) void epi_kernel(const float* __restrict__ ema_w,
                                                  const float* __restrict__ dw,
                                                  const float* __restrict__ cs_pre,
                                                  const float* __restrict__ nptr,
                                                  float* __restrict__ new_cb,
                                                  float* __restrict__ new_w,
                                                  float* __restrict__ cs_out) {
    int gid = blockIdx.x * 256 + threadIdx.x;   // 0 .. 1048575
    int k = gid >> 8, d = gid & 255;
    float n = *nptr;
    float csp = cs_pre[k];
    float cs = (csp + EPSF) / (n + (float)KEMB * EPSF) * n;
    float w = ema_w[gid] * DECAYF + (1.0f - DECAYF) * dw[gid];
    new_w[gid] = w;
    new_cb[gid] = w / cs;
    if (d == 0) cs_out[k] = cs;
}

extern "C" void kernel_launch(void* const* d_in, const int* in_sizes, int n_in,
                              void* d_out, int out_size, void* d_ws, size_t ws_size,
                              hipStream_t stream) {
    const float* xg     = (const float*)d_in[0];   // [32768,256]
    const float* cbg    = (const float*)d_in[1];   // [4096,256]
    const float* ema_w  = (const float*)d_in[2];   // [4096,256]
    const float* ema_cs = (const float*)d_in[3];   // [4096]

    float* out = (float*)d_out;
    unsigned char* wsb = (unsigned char*)d_ws;

    float* quant  = out + OFF_Q;
    float* enc    = out + OFF_E;
    float* new_cb = out + OFF_CB;
    float* new_w  = out + OFF_W;
    float* cs_out = out + OFF_CS;

    unsigned short* Ahat = (unsigned short*)(wsb + B_AHAT);
    unsigned short* Bhat = (unsigned short*)(wsb + B_BHAT);
    float4* part   = (float4*)(wsb + B_PART);
    float* ce      = (float*)(wsb + B_CE);
    float* counts  = (float*)(wsb + B_CNT);
    float* cs_pre  = (float*)(wsb + B_CSP);
    float* nptr    = (float*)(wsb + B_NPTR);
    int*   flagCnt = (int*)(wsb + B_FLAGC);
    int*   tokIdx  = (int*)(wsb + B_TIDX);
    int*   flist   = (int*)(wsb + B_FLIST);
    float* dw      = (float*)(wsb + B_DW);

    // zero-init (d_out / d_ws are poisoned with 0xAA before every call)
    hipMemsetAsync(enc, 0, (size_t)NTOK * KEMB * sizeof(float), stream);   // 512 MB one-hot zeros
    hipMemsetAsync(counts, 0, KEMB * sizeof(float), stream);
    hipMemsetAsync(nptr, 0, 8, stream);                                    // n + flagCount
    hipMemsetAsync(dw, 0, (size_t)KEMB * DDIM * sizeof(float), stream);

    splitA_kernel<<<(NTOK * 32) / 256, 256, 0, stream>>>(xg, Ahat);
    splitB_kernel<<<(KEMB * 32) / 256, 256, 0, stream>>>(cbg, Bhat);
    ce_kernel<<<KEMB / 4, 256, 0, stream>>>(cbg, ce);
    gemm_argmin_kernel<<<dim3(NTOK / 128, KEMB / 128), 256, 0, stream>>>(Ahat, Bhat, ce, part);
    argmin_reduce_kernel<<<NTOK / 4, 256, 0, stream>>>(part, tokIdx, flist, flagCnt);
    refine_kernel<<<256, 256, 0, stream>>>(xg, cbg, tokIdx, flist, flagCnt);
    scatter_kernel<<<NTOK, 64, 0, stream>>>(xg, cbg, tokIdx, quant, enc, dw, counts);
    cs_kernel<<<KEMB / 256, 256, 0, stream>>>(ema_cs, counts, cs_pre, nptr);
    epi_kernel<<<(KEMB * DDIM) / 256, 256, 0, stream>>>(ema_w, dw, cs_pre, nptr,
                                                        new_cb, new_w, cs_out);
}

// Round 3
// 1186.902 us; speedup vs baseline: 2.0033x; 1.0810x over previous
//
#include <hip/hip_runtime.h>
#include <hip/hip_bf16.h>

#define NTOK 32768
#define KEMB 4096
#define DDIM 256
#define DECAYF 0.99f
#define EPSF 1e-5f

// ---------------- workspace layout (BYTE offsets) ----------------
#define B_AHAT  0ull          // 32768*768 bf16 = 50331648 B  [Xh|Xl|Xh]
#define B_BHAT  50331648ull   // 4096*768 bf16  = 6291456 B   [Ch|Ch|Cl]
#define B_PART  56623104ull   // 32768*64 float4 = 33554432 B  per-64col-chunk (b1,b2,idx)
#define B_CE    90177536ull   // 4096 f32
#define B_CNT   90193920ull   // 4096 f32
#define B_CSP   90210304ull   // 4096 f32
#define B_NPTR  90226688ull   // f32 n
#define B_FLAGC 90226692ull   // int flag count
#define B_TIDX  90226752ull   // 32768 int
#define B_FLIST 90357824ull   // 32768 int
#define B_DW    90488896ull   // 4096*256 f32 = 4194304 B
// total ~94.7 MB

// ---------------- output layout (float offsets) ----------------
#define OFF_Q  0ull                 // quantized  [32768,256]
#define OFF_E  8388608ull           // encodings  [32768,4096]
#define OFF_CB 142606336ull         // new_codebook [4096,256]
#define OFF_W  143654912ull         // new_ema_w    [4096,256]
#define OFF_CS 144703488ull         // cs [4096]

typedef __attribute__((ext_vector_type(8))) unsigned short us8;
typedef __attribute__((ext_vector_type(8))) short bf16x8;
typedef __attribute__((ext_vector_type(4))) float f32x4;

// ---- split fp32 -> (hi, lo) bf16, Ahat = [Xh | Xl | Xh] along K ----
__global__ __launch_bounds__(256) void splitA_kernel(const float* __restrict__ x,
                                                     unsigned short* __restrict__ Ahat) {
    int gid = blockIdx.x * 256 + threadIdx.x;   // 0 .. 32768*32-1
    int i = gid >> 5;
    int c = gid & 31;                           // 8-elem chunk
    const float* xp = x + (size_t)i * DDIM + c * 8;
    us8 hi, lo;
    #pragma unroll
    for (int t = 0; t < 8; ++t) {
        float v = xp[t];
        __hip_bfloat16 h = __float2bfloat16(v);
        float hf = __bfloat162float(h);
        __hip_bfloat16 l = __float2bfloat16(v - hf);
        hi[t] = *(unsigned short*)&h;
        lo[t] = *(unsigned short*)&l;
    }
    unsigned short* row = Ahat + (size_t)i * 768 + c * 8;
    *(us8*)(row)       = hi;
    *(us8*)(row + 256) = lo;
    *(us8*)(row + 512) = hi;
}

// ---- Bhat = [Ch | Ch | Cl] along K; also emits ce[j] = ||c_j||^2 (fp32) ----
__global__ __launch_bounds__(256) void splitB_kernel(const float* __restrict__ cb,
                                                     unsigned short* __restrict__ Bhat,
                                                     float* __restrict__ ce) {
    int gid = blockIdx.x * 256 + threadIdx.x;   // 0 .. 4096*32-1
    int j = gid >> 5;
    int c = gid & 31;
    const float* cp = cb + (size_t)j * DDIM + c * 8;
    us8 hi, lo;
    float nrm = 0.0f;
    #pragma unroll
    for (int t = 0; t < 8; ++t) {
        float v = cp[t];
        nrm = fmaf(v, v, nrm);
        __hip_bfloat16 h = __float2bfloat16(v);
        float hf = __bfloat162float(h);
        __hip_bfloat16 l = __float2bfloat16(v - hf);
        hi[t] = *(unsigned short*)&h;
        lo[t] = *(unsigned short*)&l;
    }
    unsigned short* row = Bhat + (size_t)j * 768 + c * 8;
    *(us8*)(row)       = hi;
    *(us8*)(row + 256) = hi;
    *(us8*)(row + 512) = lo;
    // reduce ||c_j||^2 across the 32 threads of row j (32-lane subgroup)
    #pragma unroll
    for (int m = 16; m > 0; m >>= 1) nrm += __shfl_xor(nrm, m, 32);
    if (c == 0) ce[j] = nrm;
}

// ---- bf16 MFMA GEMM (M=32768, N=4096, K=768) with fused per-row argmin.
// 128x128 tile, BK=64, global_load_lds width-16, XOR-swizzled chunk staging
// (LDS[row][c] holds global chunk c^(row&7)) -> conflict-free ds_read_b128.
__global__ __launch_bounds__(256) void gemm_argmin_kernel(
        const unsigned short* __restrict__ Ahat,
        const unsigned short* __restrict__ Bhat,
        const float* __restrict__ ceg,
        float4* __restrict__ part) {
    __shared__ unsigned short As[128 * 64];   // 16 KB
    __shared__ unsigned short Bs[128 * 64];   // 16 KB
    const int tid  = threadIdx.x;
    const int lane = tid & 63;
    const int wave = tid >> 6;
    const int wm = wave >> 1, wn = wave & 1;  // 2x2 wave grid, 64x64 per wave
    const int mb = blockIdx.x, nb = blockIdx.y;
    const int col = lane & 15, q = lane >> 4;
    const int cswz = q ^ (col & 7);           // reader chunk swizzle base

    // staging: thread t handles (row = n*32 + t/8, chunk = t%8), fetches the
    // XOR-swizzled global chunk so LDS stays lane-contiguous for the DMA.
    const int srow = tid >> 3;
    const int sswz = (tid & 7) ^ (srow & 7);
    const unsigned short* ag = Ahat + (size_t)(mb * 128 + srow) * 768 + sswz * 8;
    const unsigned short* bg = Bhat + (size_t)(nb * 128 + srow) * 768 + sswz * 8;

    f32x4 zero = {0.f, 0.f, 0.f, 0.f};
    f32x4 acc[4][4];
    #pragma unroll
    for (int i = 0; i < 4; ++i)
        #pragma unroll
        for (int j = 0; j < 4; ++j) acc[i][j] = zero;

    for (int kt = 0; kt < 12; ++kt) {
        __syncthreads();
        #pragma unroll
        for (int n = 0; n < 4; ++n) {
            __builtin_amdgcn_global_load_lds(
                (const __attribute__((address_space(1))) void*)(ag + (size_t)n * 32 * 768 + kt * 64),
                (__attribute__((address_space(3))) void*)(As + n * 2048 + tid * 8), 16, 0, 0);
            __builtin_amdgcn_global_load_lds(
                (const __attribute__((address_space(1))) void*)(bg + (size_t)n * 32 * 768 + kt * 64),
                (__attribute__((address_space(3))) void*)(Bs + n * 2048 + tid * 8), 16, 0, 0);
        }
        __syncthreads();

        const bf16x8* Av = (const bf16x8*)As;
        const bf16x8* Bv = (const bf16x8*)Bs;
        #pragma unroll
        for (int ks = 0; ks < 2; ++ks) {
            bf16x8 a[4], b[4];
            #pragma unroll
            for (int i = 0; i < 4; ++i)
                a[i] = Av[(wm * 64 + i * 16 + col) * 8 + (cswz ^ (ks * 4))];
            #pragma unroll
            for (int j = 0; j < 4; ++j)
                b[j] = Bv[(wn * 64 + j * 16 + col) * 8 + (cswz ^ (ks * 4))];
            #pragma unroll
            for (int i = 0; i < 4; ++i)
                #pragma unroll
                for (int j = 0; j < 4; ++j)
                    acc[i][j] = __builtin_amdgcn_mfma_f32_16x16x32_bf16(a[i], b[j], acc[i][j], 0, 0, 0);
        }
    }

    // epilogue: s = ||c||^2 - 2*dot. C/D layout: col = lane&15, row = q*4+reg.
    float ce_j[4];
    #pragma unroll
    for (int j = 0; j < 4; ++j) ce_j[j] = ceg[nb * 128 + wn * 64 + j * 16 + col];

    #pragma unroll
    for (int i = 0; i < 4; ++i) {
        #pragma unroll
        for (int r = 0; r < 4; ++r) {
            float b1 = 3.4e38f, b2 = 3.4e38f;
            int i1 = 0x7fffffff;
            #pragma unroll
            for (int j = 0; j < 4; ++j) {
                float s = ce_j[j] - 2.0f * acc[i][j][r];
                int n = nb * 128 + wn * 64 + j * 16 + col;
                if (s < b1) { b2 = b1; b1 = s; i1 = n; }
                else if (s < b2) { b2 = s; }
            }
            #pragma unroll
            for (int m = 1; m < 16; m <<= 1) {
                float ob1 = __shfl_xor(b1, m, 16);
                float ob2 = __shfl_xor(b2, m, 16);
                int   oi  = __shfl_xor(i1, m, 16);
                bool take = (ob1 < b1) || (ob1 == b1 && oi < i1);
                float nb2 = take ? fminf(b1, ob2) : fminf(b2, ob1);
                if (take) { b1 = ob1; i1 = oi; }
                b2 = nb2;
            }
            if (col == i * 4 + r) {   // unique writer lane per (q,i,r)
                int mrow = mb * 128 + wm * 64 + i * 16 + q * 4 + r;
                float4 p;
                p.x = b1; p.y = b2; p.z = __int_as_float(i1); p.w = 0.0f;
                part[(size_t)mrow * 64 + nb * 2 + wn] = p;
            }
        }
    }
}

// ---- merge 64 column-chunk partials per row; flag near-ties ----
__global__ __launch_bounds__(256) void argmin_reduce_kernel(
        const float4* __restrict__ part,
        int* __restrict__ tokIdx,
        int* __restrict__ flist,
        int* __restrict__ flagCount) {
    int row = blockIdx.x * 4 + (threadIdx.x >> 6);
    int lane = threadIdx.x & 63;
    float4 p = part[(size_t)row * 64 + lane];
    float b1 = p.x, b2 = p.y;
    int i1 = __float_as_int(p.z);
    #pragma unroll
    for (int m = 1; m < 64; m <<= 1) {
        float ob1 = __shfl_xor(b1, m);
        float ob2 = __shfl_xor(b2, m);
        int   oi  = __shfl_xor(i1, m);
        bool take = (ob1 < b1) || (ob1 == b1 && oi < i1);
        float nb2 = take ? fminf(b1, ob2) : fminf(b2, ob1);
        if (take) { b1 = ob1; i1 = oi; }
        b2 = nb2;
    }
    if (lane == 0) {
        tokIdx[row] = i1;
        if (b2 - b1 < 0.0625f) {   // near-tie vs split-bf16 error (~3e-4): refine
            int slot = atomicAdd(flagCount, 1);
            flist[slot] = row;
        }
    }
}

// ---- fp64 exact re-resolution of flagged tokens ----
__global__ __launch_bounds__(256) void refine_kernel(const float* __restrict__ xg,
                                                     const float* __restrict__ cb,
                                                     int* __restrict__ tokIdx,
                                                     const int* __restrict__ flagList,
                                                     const int* __restrict__ flagCount) {
    __shared__ double xs[256];
    __shared__ double rb[256];
    __shared__ int    ri[256];
    int nf = *flagCount;
    for (int f = blockIdx.x; f < nf; f += gridDim.x) {
        int tok = flagList[f];
        __syncthreads();
        xs[threadIdx.x] = (double)xg[(size_t)tok * DDIM + threadIdx.x];
        __syncthreads();
        double best = 1e300;
        int bi = 0x7fffffff;
        for (int kk = 0; kk < KEMB / 256; ++kk) {
            int k = kk * 256 + threadIdx.x;
            const float* e = cb + (size_t)k * DDIM;
            double s = 0.0;
            for (int d4 = 0; d4 < DDIM / 4; ++d4) {
                float4 e4 = *(const float4*)(e + d4 * 4);
                double e0 = (double)e4.x, e1 = (double)e4.y;
                double e2 = (double)e4.z, e3 = (double)e4.w;
                s += e0 * (e0 - 2.0 * xs[d4 * 4 + 0]) + e1 * (e1 - 2.0 * xs[d4 * 4 + 1])
                   + e2 * (e2 - 2.0 * xs[d4 * 4 + 2]) + e3 * (e3 - 2.0 * xs[d4 * 4 + 3]);
            }
            if (s < best) { best = s; bi = k; }
        }
        rb[threadIdx.x] = best;
        ri[threadIdx.x] = bi;
        __syncthreads();
        if (threadIdx.x == 0) {
            double b = rb[0]; int i1 = ri[0];
            for (int c = 1; c < 256; ++c) {
                if (rb[c] < b || (rb[c] == b && ri[c] < i1)) { b = rb[c]; i1 = ri[c]; }
            }
            tokIdx[tok] = i1;
        }
        __syncthreads();
    }
}

// ---- per-token scatter: FULL one-hot row (replaces 512MB memset pass),
// quantized row, dw/counts atomics. One block per token, 256 threads. ----
__global__ __launch_bounds__(256) void scatter_kernel(const float* __restrict__ xg,
                                                      const float* __restrict__ cb,
                                                      const int* __restrict__ tokIdx,
                                                      float* __restrict__ quant,
                                                      float* __restrict__ enc,
                                                      float* __restrict__ dw,
                                                      float* __restrict__ counts) {
    int tok = blockIdx.x;
    int tid = threadIdx.x;
    int k = tokIdx[tok];
    // one-hot row: 4096 floats = 1024 float4, 4 per thread (streaming stores)
    float4* er = (float4*)(enc + (size_t)tok * KEMB);
    int kf4 = k >> 2, kc = k & 3;
    #pragma unroll
    for (int v = 0; v < 4; ++v) {
        int f4 = v * 256 + tid;
        float4 val = {0.f, 0.f, 0.f, 0.f};
        if (f4 == kf4) ((float*)&val)[kc] = 1.0f;
        er[f4] = val;
    }
    if (tid < 64) {
        float4 e = *(const float4*)(cb + (size_t)k * DDIM + tid * 4);
        *(float4*)(quant + (size_t)tok * DDIM + tid * 4) = e;
        float4 xv = *(const float4*)(xg + (size_t)tok * DDIM + tid * 4);
        float* dwr = dw + (size_t)k * DDIM + tid * 4;
        atomicAdd(dwr + 0, xv.x);
        atomicAdd(dwr + 1, xv.y);
        atomicAdd(dwr + 2, xv.z);
        atomicAdd(dwr + 3, xv.w);
    }
    if (tid == 128) atomicAdd(counts + k, 1.0f);
}

// ---- cs_pre = ema_cs*decay + (1-decay)*counts ; n = sum(cs_pre) ----
__global__ __launch_bounds__(256) void cs_kernel(const float* __restrict__ ema_cs,
                                                 const float* __restrict__ counts,
                                                 float* __restrict__ cs_pre,
                                                 float* __restrict__ nptr) {
    int k = blockIdx.x * 256 + threadIdx.x;
    float c = ema_cs[k] * DECAYF + (1.0f - DECAYF) * counts[k];
    cs_pre[k] = c;
    float s = c;
    #pragma unroll
    for (int o = 32; o > 0; o >>= 1) s += __shfl_down(s, o);
    __shared__ float red[4];
    int lane = threadIdx.x & 63, w = threadIdx.x >> 6;
    if (lane == 0) red[w] = s;
    __syncthreads();
    if (threadIdx.x == 0) atomicAdd(nptr, red[0] + red[1] + red[2] + red[3]);
}

// ---- epilogue: new_ema_w, laplace-smoothed cs, new_codebook ----
__global__ __launch_bounds__(256) void epi_kernel(const float* __restrict__ ema_w,
                                                  const float* __restrict__ dw,
                                                  const float* __restrict__ cs_pre,
                                                  const float* __restrict__ nptr,
                                                  float* __restrict__ new_cb,
                                                  float* __restrict__ new_w,
                                                  float* __restrict__ cs_out) {
    int gid = blockIdx.x * 256 + threadIdx.x;   // 0 .. 1048575
    int k = gid >> 8, d = gid & 255;
    float n = *nptr;
    float csp = cs_pre[k];
    float cs = (csp + EPSF) / (n + (float)KEMB * EPSF) * n;
    float w = ema_w[gid] * DECAYF + (1.0f - DECAYF) * dw[gid];
    new_w[gid] = w;
    new_cb[gid] = w / cs;
    if (d == 0) cs_out[k] = cs;
}

extern "C" void kernel_launch(void* const* d_in, const int* in_sizes, int n_in,
                              void* d_out, int out_size, void* d_ws, size_t ws_size,
                              hipStream_t stream) {
    const float* xg     = (const float*)d_in[0];   // [32768,256]
    const float* cbg    = (const float*)d_in[1];   // [4096,256]
    const float* ema_w  = (const float*)d_in[2];   // [4096,256]
    const float* ema_cs = (const float*)d_in[3];   // [4096]

    float* out = (float*)d_out;
    unsigned char* wsb = (unsigned char*)d_ws;

    float* quant  = out + OFF_Q;
    float* enc    = out + OFF_E;
    float* new_cb = out + OFF_CB;
    float* new_w  = out + OFF_W;
    float* cs_out = out + OFF_CS;

    unsigned short* Ahat = (unsigned short*)(wsb + B_AHAT);
    unsigned short* Bhat = (unsigned short*)(wsb + B_BHAT);
    float4* part   = (float4*)(wsb + B_PART);
    float* ce      = (float*)(wsb + B_CE);
    float* counts  = (float*)(wsb + B_CNT);
    float* cs_pre  = (float*)(wsb + B_CSP);
    float* nptr    = (float*)(wsb + B_NPTR);
    int*   flagCnt = (int*)(wsb + B_FLAGC);
    int*   tokIdx  = (int*)(wsb + B_TIDX);
    int*   flist   = (int*)(wsb + B_FLIST);
    float* dw      = (float*)(wsb + B_DW);

    // zero-init (d_out / d_ws are poisoned with 0xAA before every call).
    // enc is now fully written by scatter_kernel -> no 512MB memset pass.
    hipMemsetAsync(counts, 0, KEMB * sizeof(float), stream);
    hipMemsetAsync(nptr, 0, 8, stream);                                    // n + flagCount
    hipMemsetAsync(dw, 0, (size_t)KEMB * DDIM * sizeof(float), stream);

    splitA_kernel<<<(NTOK * 32) / 256, 256, 0, stream>>>(xg, Ahat);
    splitB_kernel<<<(KEMB * 32) / 256, 256, 0, stream>>>(cbg, Bhat, ce);
    gemm_argmin_kernel<<<dim3(NTOK / 128, KEMB / 128), 256, 0, stream>>>(Ahat, Bhat, ce, part);
    argmin_reduce_kernel<<<NTOK / 4, 256, 0, stream>>>(part, tokIdx, flist, flagCnt);
    refine_kernel<<<256, 256, 0, stream>>>(xg, cbg, tokIdx, flist, flagCnt);
    scatter_kernel<<<NTOK, 256, 0, stream>>>(xg, cbg, tokIdx, quant, enc, dw, counts);
    cs_kernel<<<KEMB / 256, 256, 0, stream>>>(ema_cs, counts, cs_pre, nptr);
    epi_kernel<<<(KEMB * DDIM) / 256, 256, 0, stream>>>(ema_w, dw, cs_pre, nptr,
                                                        new_cb, new_w, cs_out);
}